// Round 12
// baseline (121.010 us; speedup 1.0000x reference)
//
#include <hip/hip_runtime.h>

#define NN 1024
#define MM 1024
#define DD 256

typedef float floatx2 __attribute__((ext_vector_type(2)));

__device__ __forceinline__ float rcp_fast(float x) { return __builtin_amdgcn_rcpf(x); }

// ---- hand-emitted packed-fp32 VOP3P (LLVM won't auto-form these from ext-vector f32) ----
// NOTE (rounds 10/11): this kernel sits at the SGPR-allocation cliff (SGPR=112).
// Any transform extending the "s"-constraint live ranges (manual prefetch
// rotation, #pragma unroll >1 on the c8 loop) silently miscompiles -> NaN.
// Do NOT re-attempt ILP transforms on this form.
__device__ __forceinline__ floatx2 pk_mul(floatx2 a, floatx2 b) {
    floatx2 d;
    asm("v_pk_mul_f32 %0, %1, %2" : "=v"(d) : "v"(a), "v"(b));
    return d;
}
__device__ __forceinline__ floatx2 pk_fma(floatx2 a, floatx2 b, floatx2 c) {
    floatx2 d;
    asm("v_pk_fma_f32 %0, %1, %2, %3" : "=v"(d) : "v"(a), "v"(b), "v"(c));
    return d;
}
// uniform-operand variants: b lives in an even-aligned SGPR pair (1 SGPR read/instr — legal)
__device__ __forceinline__ floatx2 pk_mul_vs(floatx2 a, floatx2 b) {
    floatx2 d;
    asm("v_pk_mul_f32 %0, %1, %2" : "=v"(d) : "v"(a), "s"(b));
    return d;
}
__device__ __forceinline__ floatx2 pk_fma_vs(floatx2 a, floatx2 b, floatx2 c) {
    floatx2 d;
    asm("v_pk_fma_f32 %0, %1, %2, %3" : "=v"(d) : "v"(a), "s"(b), "v"(c));
    return d;
}

// ---------------- K1: fused dual GEMM + exp epilogue ----------------
// blocks 0..127:   q = f_r @ W_w^T + W_b    -> Eq[n][d] = exp(2q)  (clamped +-5)
// blocks 128..255: k = f_rp @ Wp_w^T + Wp_b -> Ek4 in d-quad-interleaved layout:
//   element (m, d) at Ek4[(d>>2)*4*MM + m*4 + (d&3)] — so K2's per-m float4 load
//   of 4 consecutive d is coalesced across consecutive-m lanes.
// Block 0 also zeroes d_out for K3's atomicAdd.
__global__ __launch_bounds__(256) void gemm_exp_kernel(
    const float* __restrict__ f_r,  const float* __restrict__ W_w,  const float* __restrict__ W_b,
    const float* __restrict__ f_rp, const float* __restrict__ Wp_w, const float* __restrict__ Wp_b,
    float* __restrict__ Eq, float* __restrict__ Ek4, float* __restrict__ out0)
{
    __shared__ float As[32][36];   // [k][r]
    __shared__ float Bs[32][68];   // [k][d]
    __shared__ float4 T4[32][17];  // k-path exchange: [m_local][dq_local], +1 pad

    const int b = blockIdx.x;
    const int t = threadIdx.x;
    if (b == 0) out0[t] = 0.f;     // zero d_out (256 floats)

    const int mat  = b >> 7;
    const int tile = b & 127;
    const int rt = tile & 31, dt = tile >> 5;
    const float* __restrict__ A    = mat ? f_rp : f_r;
    const float* __restrict__ B    = mat ? Wp_w : W_w;
    const float* __restrict__ bias = mat ? Wp_b : W_b;

    const int tx = t & 15, ty = t >> 4;          // tx -> 4 d-cols (one d-quad), ty -> 2 r-rows
    const int r0 = rt * 32, d0 = dt * 64;
    const int ar = t >> 3, ak = (t & 7) * 4;     // A stage: 32 rows x 32 k
    const int br = t >> 2, bk = (t & 3) * 8;     // B stage: 64 rows x 32 k

    float acc[2][4];
    #pragma unroll
    for (int i = 0; i < 2; ++i)
        #pragma unroll
        for (int j = 0; j < 4; ++j) acc[i][j] = 0.f;

    for (int kk = 0; kk < DD; kk += 32) {
        float4 av  = *(const float4*)(A + (size_t)(r0 + ar) * DD + kk + ak);
        float4 bv0 = *(const float4*)(B + (size_t)(d0 + br) * DD + kk + bk);
        float4 bv1 = *(const float4*)(B + (size_t)(d0 + br) * DD + kk + bk + 4);
        __syncthreads();
        As[ak + 0][ar] = av.x; As[ak + 1][ar] = av.y; As[ak + 2][ar] = av.z; As[ak + 3][ar] = av.w;
        Bs[bk + 0][br] = bv0.x; Bs[bk + 1][br] = bv0.y; Bs[bk + 2][br] = bv0.z; Bs[bk + 3][br] = bv0.w;
        Bs[bk + 4][br] = bv1.x; Bs[bk + 5][br] = bv1.y; Bs[bk + 6][br] = bv1.z; Bs[bk + 7][br] = bv1.w;
        __syncthreads();
        #pragma unroll
        for (int k = 0; k < 32; ++k) {
            float2 a2 = *(const float2*)&As[k][ty * 2];
            float4 b4 = *(const float4*)&Bs[k][tx * 4];
            float aa[2] = {a2.x, a2.y};
            float bb[4] = {b4.x, b4.y, b4.z, b4.w};
            #pragma unroll
            for (int i = 0; i < 2; ++i)
                #pragma unroll
                for (int j = 0; j < 4; ++j)
                    acc[i][j] = fmaf(aa[i], bb[j], acc[i][j]);
        }
    }

    float bj[4];
    #pragma unroll
    for (int j = 0; j < 4; ++j) bj[j] = bias[d0 + tx * 4 + j];

    float e[2][4];
    #pragma unroll
    for (int i = 0; i < 2; ++i)
        #pragma unroll
        for (int j = 0; j < 4; ++j) {
            float v = acc[i][j] + bj[j];
            // +-5: tanh(5)=0.9999092 (error 9e-5, negligible after w-weighting);
            // also bounds the no-max exp in K2: |s~| <= 2*sum|w| <= 32 -> e^32 << fp32 max.
            v = fminf(fmaxf(v, -5.f), 5.f);
            e[i][j] = __expf(2.f * v);
        }

    if (mat == 0) {
        #pragma unroll
        for (int i = 0; i < 2; ++i)
            *(float4*)&Eq[(size_t)(r0 + ty * 2 + i) * DD + d0 + tx * 4] =
                make_float4(e[i][0], e[i][1], e[i][2], e[i][3]);
    } else {
        // thread holds m = r0+ty*2+i, d-quad dq_local = tx, j = d&3 contiguous.
        __syncthreads();
        #pragma unroll
        for (int i = 0; i < 2; ++i)
            T4[ty * 2 + i][tx] = make_float4(e[i][0], e[i][1], e[i][2], e[i][3]);
        __syncthreads();
        const int sm = t & 31, sq = t >> 5;   // sm -> m_local, sq -> dq_local (2 halves)
        #pragma unroll
        for (int h = 0; h < 2; ++h) {
            const int dql = sq + 8 * h;
            float4 v = T4[sm][dql];
            // coalesced: consecutive sm lanes -> consecutive m -> +16B stride
            *(float4*)&Ek4[(size_t)((d0 >> 2) + dql) * (4 * MM) + (size_t)(r0 + sm) * 4] = v;
        }
    }
}

// ---------------- K2: n=8 m-split mega kernel, pk phase A (round-9 form, verified) ----------------
// 256 blocks x 1024 thr; block = (n-oct = bid>>1, m-half = bid&1). 1 block/CU.
// Phase A: lane owns ONE m (t&511), tg = t>>9 -> d-half; 14 pk + 2 rcp per (n,8d);
//   Ek4 float4 = 4 consecutive d at this m (coalesced); q/w via wave-uniform
//   s_loads feeding SGPR-pair pk operands.
// Phase B: 2-slab combine + NO-MAX exp (|s~|<=32 provably); partial denom -> Sp.
// Phase C: ctx~_half = e @ frp[m-half]; 16 ranges x 64 d-quads, all 8 n/thread.
__global__ __launch_bounds__(1024, 4) void fused_attn_kernel(
    const float* __restrict__ Eq, const float* __restrict__ Ek4,
    const float* __restrict__ w_w, const float* __restrict__ frp,
    const float* __restrict__ wp_w,
    float* __restrict__ ctxA, float* __restrict__ ctxB,
    float* __restrict__ SpA, float* __restrict__ SpB,
    float* __restrict__ sA,  float* __restrict__ sB)
{
    // union region: part (phase A->B, 32KB) aliases ctxred (phase C, 128KB);
    // lifetimes separated by the phase-B barrier.
    __shared__ __align__(16) char usm_raw[131072];
    float (*part)[8][512]   = (float (*)[8][512])(void*)usm_raw;   // [2][8][512] 32KB
    float4 (*ctxred)[8][64] = (float4 (*)[8][64])(void*)usm_raw;   // [16][8][64] 128KB
    __shared__ float alsm[8][512];   // 16KB unnormalized e
    __shared__ float redsm[8][2];
    __shared__ float redsc[8][2];

    const int t  = threadIdx.x;
    const int bm = blockIdx.x & 1;
    const int n0 = (blockIdx.x >> 1) * 8;
    const int m0 = bm * 512;

    // ---- Phase A: lane = 1 m, tg = d-half of 128; 16 chunks of 8 d ----
    const int m_l = t & 511;
    const int tg  = t >> 9;                                   // wave-uniform
    const int dbase = __builtin_amdgcn_readfirstlane(tg * 128);
    const float* __restrict__ eqb = Eq + (size_t)n0 * DD + dbase;
    const float* __restrict__ wwb = w_w + dbase;
    const float* __restrict__ ekb = Ek4 + (size_t)(dbase >> 2) * (4 * MM) + (size_t)(m0 + m_l) * 4;

    const floatx2 one2 = {1.f, 1.f};
    floatx2 acc[8];
    #pragma unroll
    for (int n = 0; n < 8; ++n) acc[n] = (floatx2){0.f, 0.f};

    for (int c8 = 0; c8 < 16; ++c8) {
        float4 ekA = *(const float4*)(ekb + (size_t)(2 * c8 + 0) * (4 * MM));
        float4 ekB = *(const float4*)(ekb + (size_t)(2 * c8 + 1) * (4 * MM));
        floatx2 ek01 = {ekA.x, ekA.y}, ek23 = {ekA.z, ekA.w};
        floatx2 ek45 = {ekB.x, ekB.y}, ek67 = {ekB.z, ekB.w};
        const int db = c8 * 8;
        floatx2 w01 = *(const floatx2*)(wwb + db + 0);   // uniform -> SGPR pairs
        floatx2 w23 = *(const floatx2*)(wwb + db + 2);
        floatx2 w45 = *(const floatx2*)(wwb + db + 4);
        floatx2 w67 = *(const floatx2*)(wwb + db + 6);
        #pragma unroll
        for (int n = 0; n < 8; ++n) {
            const float* qn = eqb + (size_t)n * DD + db;   // uniform -> s_load
            floatx2 q01 = *(const floatx2*)(qn + 0);
            floatx2 q23 = *(const floatx2*)(qn + 2);
            floatx2 q45 = *(const floatx2*)(qn + 4);
            floatx2 q67 = *(const floatx2*)(qn + 6);
            // x_d = Eq*Ek + 1 (per-half independent d's)
            floatx2 x01 = pk_fma_vs(ek01, q01, one2);
            floatx2 x23 = pk_fma_vs(ek23, q23, one2);
            floatx2 x45 = pk_fma_vs(ek45, q45, one2);
            floatx2 x67 = pk_fma_vs(ek67, q67, one2);
            // level 1: w/x pairwise combine
            floatx2 den1 = pk_mul(x01, x23);
            floatx2 num1 = pk_fma_vs(x01, w23, pk_mul_vs(x23, w01));
            floatx2 den2 = pk_mul(x45, x67);
            floatx2 num2 = pk_fma_vs(x45, w67, pk_mul_vs(x67, w45));
            // level 2: 4-way products (<= e^80, fp32-safe)
            floatx2 DEN = pk_mul(den1, den2);
            floatx2 NUM = pk_fma(num2, den1, pk_mul(num1, den2));
            floatx2 r2; r2.x = rcp_fast(DEN.x); r2.y = rcp_fast(DEN.y);
            acc[n] = pk_fma(NUM, r2, acc[n]);
        }
    }

    #pragma unroll
    for (int n = 0; n < 8; ++n)
        part[tg][n][m_l] = acc[n].x + acc[n].y;   // conflict-free: stride-1 lanes
    __syncthreads();

    // ---- Phase B: combine d-halves + no-max exp; thread -> (n = t>>7, 4 m = t&127) ----
    {
        const int bn = t >> 7, bj = t & 127;
        float4 a0 = *(const float4*)&part[0][bn][4 * bj];
        float4 a1 = *(const float4*)&part[1][bn][4 * bj];
        float e0 = __expf(-2.f * (a0.x + a1.x));   // bounded: |s~| <= 32
        float e1 = __expf(-2.f * (a0.y + a1.y));
        float e2 = __expf(-2.f * (a0.z + a1.z));
        float e3 = __expf(-2.f * (a0.w + a1.w));
        *(float4*)&alsm[bn][4 * bj] = make_float4(e0, e1, e2, e3);
        float sm = (e0 + e1) + (e2 + e3);
        #pragma unroll
        for (int off = 32; off > 0; off >>= 1) sm += __shfl_xor(sm, off);
        if ((t & 63) == 0) redsm[bn][(t >> 6) & 1] = sm;   // bn wave-uniform (t>>7)
    }
    __syncthreads();   // alsm+redsm ready; part dead -> ctxred alias safe
    if (t < 8) {
        float* Sp = bm ? SpB : SpA;
        Sp[n0 + t] = redsm[t][0] + redsm[t][1];
    }

    // ---- Phase C: ctx~ = e @ frp; thread = (m-range rr = t>>6, d-quad cc = t&63), 8 n ----
    const int rr = t >> 6;        // 16 ranges of 32 m (wave-uniform)
    const int cc = t & 63;        // d-cols 4cc..4cc+3
    floatx2 axl[8], axh[8];
    #pragma unroll
    for (int n = 0; n < 8; ++n) { axl[n] = (floatx2){0.f,0.f}; axh[n] = (floatx2){0.f,0.f}; }
    const float* fb = frp + (size_t)(m0 + rr * 32) * DD + 4 * cc;
    for (int mq = 0; mq < 8; ++mq) {
        float alv[8][4];
        #pragma unroll
        for (int n = 0; n < 8; ++n) {
            float4 a4 = *(const float4*)&alsm[n][rr * 32 + mq * 4];   // uniform -> broadcast
            alv[n][0] = a4.x; alv[n][1] = a4.y; alv[n][2] = a4.z; alv[n][3] = a4.w;
        }
        #pragma unroll
        for (int mm = 0; mm < 4; ++mm) {
            float4 f = *(const float4*)(fb + (size_t)(mq * 4 + mm) * DD);
            floatx2 fl = {f.x, f.y}, fh = {f.z, f.w};
            #pragma unroll
            for (int n = 0; n < 8; ++n) {
                axl[n] += alv[n][mm] * fl;
                axh[n] += alv[n][mm] * fh;
            }
        }
    }
    #pragma unroll
    for (int n = 0; n < 8; ++n)
        ctxred[rr][n][cc] = make_float4(axl[n].x, axl[n].y, axh[n].x, axh[n].y);
    __syncthreads();

    // final range-reduce: thread t -> (n = t>>7, d = t&127 and d+128)
    const int fn = t >> 7, fd = t & 127;
    float s_lo = 0.f, s_hi = 0.f;
    #pragma unroll
    for (int r = 0; r < 16; ++r) {
        s_lo += ((const float*)&ctxred[r][fn][fd >> 2])[fd & 3];
        s_hi += ((const float*)&ctxred[r][fn][(fd >> 2) + 32])[fd & 3];
    }
    float* ctxP = bm ? ctxB : ctxA;
    ctxP[(size_t)(n0 + fn) * DD + fd]       = s_lo;
    ctxP[(size_t)(n0 + fn) * DD + fd + 128] = s_hi;

    // stage-2 partial score: s~_half[n] = ctx~_half[n] . wp_w
    float p = s_lo * wp_w[fd] + s_hi * wp_w[fd + 128];
    #pragma unroll
    for (int off = 32; off > 0; off >>= 1) p += __shfl_xor(p, off);
    if ((t & 63) == 0) redsc[fn][(t >> 6) & 1] = p;        // fn wave-uniform
    __syncthreads();
    if (t < 8) {
        float* sP = bm ? sB : sA;
        sP[n0 + t] = redsc[t][0] + redsc[t][1];
    }
}

// ---------------- K3: softmax over N (redundant per block) + pooled sum ----------------
// 256 blocks x 256 thr; block b handles n-rows 4b..4b+3.
// score[row] = (sA+sB)/(SpA+SpB) reconstructed from 4 scalars.
__global__ __launch_bounds__(256) void pool_kernel(
    const float* __restrict__ ctxA, const float* __restrict__ ctxB,
    const float* __restrict__ SpA,  const float* __restrict__ SpB,
    const float* __restrict__ sA,   const float* __restrict__ sB,
    float* __restrict__ out)
{
    __shared__ float red[8];
    const int t = threadIdx.x, lane = t & 63, wid = t >> 6;
    const int n0 = blockIdx.x * 4;

    float sc[4];
    #pragma unroll
    for (int i = 0; i < 4; ++i) {
        int r = t + 256 * i;
        sc[i] = (sA[r] + sB[r]) * rcp_fast(SpA[r] + SpB[r]);
    }
    float mx = fmaxf(fmaxf(sc[0], sc[1]), fmaxf(sc[2], sc[3]));
    #pragma unroll
    for (int off = 32; off > 0; off >>= 1) mx = fmaxf(mx, __shfl_xor(mx, off));
    if (lane == 0) red[wid] = mx;
    __syncthreads();
    mx = fmaxf(fmaxf(red[0], red[1]), fmaxf(red[2], red[3]));

    float se = __expf(sc[0] - mx) + __expf(sc[1] - mx) + __expf(sc[2] - mx) + __expf(sc[3] - mx);
    #pragma unroll
    for (int off = 32; off > 0; off >>= 1) se += __shfl_xor(se, off);
    if (lane == 0) red[4 + wid] = se;
    __syncthreads();
    se = red[4] + red[5] + red[6] + red[7];
    float invS = rcp_fast(se);

    float racc = 0.f;
    #pragma unroll
    for (int i = 0; i < 4; ++i) {
        int row = n0 + i;
        float invRow = rcp_fast(SpA[row] + SpB[row]);      // wave-uniform scalar loads
        float scr = (sA[row] + sB[row]) * invRow;
        float ap = __expf(scr - mx) * invS;
        float cr = (ctxA[(size_t)row * DD + t] + ctxB[(size_t)row * DD + t]) * invRow;
        racc = fmaf(ap, cr, racc);
    }
    atomicAdd(out + t, racc);
}

extern "C" void kernel_launch(void* const* d_in, const int* in_sizes, int n_in,
                              void* d_out, int out_size, void* d_ws, size_t ws_size,
                              hipStream_t stream) {
    const float* f_r  = (const float*)d_in[0];
    const float* f_rp = (const float*)d_in[1];
    const float* W_w  = (const float*)d_in[2];
    const float* W_b  = (const float*)d_in[3];
    const float* Wp_w = (const float*)d_in[4];
    const float* Wp_b = (const float*)d_in[5];
    const float* w_w  = (const float*)d_in[6];
    // d_in[7] = w_b  : cancels in softmax over m
    const float* wp_w = (const float*)d_in[8];
    // d_in[9] = wp_b : cancels in softmax over n
    float* out = (float*)d_out;

    float* ws    = (float*)d_ws;
    float* Eq    = ws;                  // 256K floats
    float* Ek4   = ws + 262144;         // 256K (d-quad-interleaved Ek)
    float* ctxA  = ws + 524288;         // 256K (unnormalized half-0 context)
    float* ctxB  = ws + 786432;         // 256K (unnormalized half-1 context)
    float* SpA   = ws + 1048576;        // 1K (half softmax denominators)
    float* SpB   = ws + 1049600;        // 1K
    float* sA    = ws + 1050624;        // 1K (half stage-2 partial scores)
    float* sB    = ws + 1051648;        // 1K

    gemm_exp_kernel<<<256, 256, 0, stream>>>(f_r, W_w, W_b, f_rp, Wp_w, Wp_b, Eq, Ek4, out);
    fused_attn_kernel<<<256, 1024, 0, stream>>>(Eq, Ek4, w_w, f_rp, wp_w,
                                                ctxA, ctxB, SpA, SpB, sA, sB);
    pool_kernel<<<256, 256, 0, stream>>>(ctxA, ctxB, SpA, SpB, sA, sB, out);
}